// Round 3
// baseline (1169.544 us; speedup 1.0000x reference)
//
#include <hip/hip_runtime.h>
#include <math.h>

// Problem constants (MixtureLowRankRNN)
#define HIDDEN_ 1024
#define RANK_ 4
#define INPUT_ 16
#define T_ 1024
#define BATCH_ 32

#define ALPHA_F 0.1f
#define KD_F    0.9f                       // 1 - ALPHA
#define KREC_F  (0.1f * (500.0f / 1024.0f)) // ALPHA * BASE_SCALE / HIDDEN

// ---- workspace layout ----
// u    : [B][T][H] floats  = ALPHA * x_t @ I^T   (134.2 MB)
// sbuf : [B][T][4] floats  = raw s_t = n^T tanh(h_{t-1})  (0.5 MB)
#define U_ELEMS  ((size_t)BATCH_ * T_ * HIDDEN_)
#define S_ELEMS  ((size_t)BATCH_ * T_ * 4)
#define WS_NEEDED ((U_ELEMS + S_ELEMS) * sizeof(float))

__device__ __forceinline__ float fast_exp2(float x) {
    return __builtin_amdgcn_exp2f(x);
}
__device__ __forceinline__ float fast_rcp(float x) {
    return __builtin_amdgcn_rcpf(x);
}
// tanh(x) = 1 - 2/(exp(2x)+1); ~1e-6 abs err, overflow-safe (-> +-1).
__device__ __forceinline__ float tanh_fast(float x) {
    float e = fast_exp2(x * 2.885390081777926815f); // 2*log2(e)
    return fmaf(-2.0f, fast_rcp(e + 1.0f), 1.0f);
}

// v += dpp_mov(v, ctrl), old=0, bound_ctrl=1 (masked reads contribute 0).
#define DPP_ADD(v, ctrl)                                                        \
    do {                                                                        \
        int _t = __builtin_amdgcn_update_dpp(0, __float_as_int(v), (ctrl), 0xf, \
                                             0xf, true);                        \
        (v) += __int_as_float(_t);                                              \
    } while (0)

// =====================================================================
// Kernel 1: u[b][t][h] = ALPHA * sum_i x[b][t][i] * I[h][i]
// One block per (b,t); 256 threads x 4 h-elements. Memory-bound on the
// 134 MB u-write; I rows are L2-resident after the first blocks.
// =====================================================================
__global__ __launch_bounds__(256) void inp_proj_kernel(
    const float* __restrict__ x, const float* __restrict__ imat,
    float* __restrict__ u)
{
    const int bt  = blockIdx.x;          // 0 .. B*T-1
    const int tid = threadIdx.x;

    __shared__ float xs[INPUT_];
    if (tid < INPUT_) xs[tid] = x[(size_t)bt * INPUT_ + tid];
    __syncthreads();

    float xr[INPUT_];
#pragma unroll
    for (int i = 0; i < INPUT_; ++i) xr[i] = xs[i];

    float o[4];
#pragma unroll
    for (int j = 0; j < 4; ++j) {
        const float* Ih = imat + (size_t)(tid * 4 + j) * INPUT_;
        float a = xr[0] * Ih[0];
#pragma unroll
        for (int i = 1; i < INPUT_; ++i) a = fmaf(xr[i], Ih[i], a);
        o[j] = ALPHA_F * a;
    }
    ((float4*)u)[(size_t)bt * (HIDDEN_ / 4) + tid] =
        make_float4(o[0], o[1], o[2], o[3]);
}

// =====================================================================
// Kernel 2: the scan. 16 blocks x 256 threads; each block carries TWO
// independent batch recurrences (2b, 2b+1) interleaved so one batch's
// issue fills the other's latency stalls. h entirely in registers
// (4 elems/thread/batch). Per step: tanh -> rank-4 partial dots ->
// 6-level DPP wave reduce -> one LDS exchange + barrier -> h update
// with prefetched u_t. Raw s_t goes to sbuf for the output filter.
// =====================================================================
__global__ __launch_bounds__(256) void rnn_scan2_kernel(
    const float* __restrict__ m,     // [H, 4]
    const float* __restrict__ n,     // [H, 4]
    const float* __restrict__ u,     // [B, T, H] (pre-scaled by ALPHA)
    float* __restrict__ sbuf)        // [B, T, 4]
{
    const int tid  = threadIdx.x;
    const int wave = tid >> 6;
    const int lane = tid & 63;
    const int bA   = blockIdx.x * 2;
    const int bB   = bA + 1;

    float hA[4], hB[4];
    float mrs[4][4];   // krec * m row (shared across batches)
    float nr[4][4];

#pragma unroll
    for (int j = 0; j < 4; ++j) {
        const int hidx = tid * 4 + j;
        hA[j] = 0.0f; hB[j] = 0.0f;
        const float4 mv = *(const float4*)(m + hidx * 4);
        mrs[j][0] = KREC_F * mv.x; mrs[j][1] = KREC_F * mv.y;
        mrs[j][2] = KREC_F * mv.z; mrs[j][3] = KREC_F * mv.w;
        const float4 nv = *(const float4*)(n + hidx * 4);
        nr[j][0] = nv.x; nr[j][1] = nv.y; nr[j][2] = nv.z; nr[j][3] = nv.w;
    }

    // partials: [parity][wave*2 + (0=A,1=B)]
    __shared__ float4 part[2][8];

    const float4* uA = (const float4*)u + (size_t)bA * T_ * (HIDDEN_ / 4);
    const float4* uB = (const float4*)u + (size_t)bB * T_ * (HIDDEN_ / 4);
    float4* sA = (float4*)sbuf + (size_t)bA * T_;
    float4* sB = (float4*)sbuf + (size_t)bB * T_;

    float4 uAc = uA[tid];            // u_0
    float4 uBc = uB[tid];

    for (int t = 0; t < T_; ++t) {
        // prefetch next step's drive (consumed next iteration)
        const int tn = (t + 1 < T_) ? (t + 1) : t;
        float4 uAn = uA[(size_t)tn * (HIDDEN_ / 4) + tid];
        float4 uBn = uB[(size_t)tn * (HIDDEN_ / 4) + tid];

        // tanh for both batches (trans ops pipelined back-to-back)
        float thA[4], thB[4];
#pragma unroll
        for (int j = 0; j < 4; ++j) { thA[j] = tanh_fast(hA[j]); thB[j] = tanh_fast(hB[j]); }

        // rank-4 partial dots, both batches
        float pA0 = thA[0]*nr[0][0], pA1 = thA[0]*nr[0][1], pA2 = thA[0]*nr[0][2], pA3 = thA[0]*nr[0][3];
        float pB0 = thB[0]*nr[0][0], pB1 = thB[0]*nr[0][1], pB2 = thB[0]*nr[0][2], pB3 = thB[0]*nr[0][3];
#pragma unroll
        for (int j = 1; j < 4; ++j) {
            pA0 = fmaf(thA[j], nr[j][0], pA0); pA1 = fmaf(thA[j], nr[j][1], pA1);
            pA2 = fmaf(thA[j], nr[j][2], pA2); pA3 = fmaf(thA[j], nr[j][3], pA3);
            pB0 = fmaf(thB[j], nr[j][0], pB0); pB1 = fmaf(thB[j], nr[j][1], pB1);
            pB2 = fmaf(thB[j], nr[j][2], pB2); pB3 = fmaf(thB[j], nr[j][3], pB3);
        }

        // 6-level DPP reduce to lane 63, 8 chains interleaved for ILP
#define LVL(c) DPP_ADD(pA0,c); DPP_ADD(pA1,c); DPP_ADD(pA2,c); DPP_ADD(pA3,c); \
               DPP_ADD(pB0,c); DPP_ADD(pB1,c); DPP_ADD(pB2,c); DPP_ADD(pB3,c)
        LVL(0x111); LVL(0x112); LVL(0x114); LVL(0x118); LVL(0x142); LVL(0x143);
#undef LVL

        if (lane == 63) {
            part[t & 1][wave * 2 + 0] = make_float4(pA0, pA1, pA2, pA3);
            part[t & 1][wave * 2 + 1] = make_float4(pB0, pB1, pB2, pB3);
        }
        __syncthreads();

        const float4 a0 = part[t & 1][0], a1 = part[t & 1][2], a2 = part[t & 1][4], a3 = part[t & 1][6];
        const float4 b0 = part[t & 1][1], b1 = part[t & 1][3], b2 = part[t & 1][5], b3 = part[t & 1][7];
        const float sA0 = (a0.x + a1.x) + (a2.x + a3.x);
        const float sA1 = (a0.y + a1.y) + (a2.y + a3.y);
        const float sA2 = (a0.z + a1.z) + (a2.z + a3.z);
        const float sA3 = (a0.w + a1.w) + (a2.w + a3.w);
        const float sB0 = (b0.x + b1.x) + (b2.x + b3.x);
        const float sB1 = (b0.y + b1.y) + (b2.y + b3.y);
        const float sB2 = (b0.z + b1.z) + (b2.z + b3.z);
        const float sB3 = (b0.w + b1.w) + (b2.w + b3.w);

        // h <- kd*h + (krec*m)@s + u_t   (6-deep chain, 8 independent)
#pragma unroll
        for (int j = 0; j < 4; ++j) {
            const float* uAp = &uAc.x;
            const float* uBp = &uBc.x;
            float aA = fmaf(sA0, mrs[j][0], uAp[j]);
            aA = fmaf(sA1, mrs[j][1], aA);
            aA = fmaf(sA2, mrs[j][2], aA);
            aA = fmaf(sA3, mrs[j][3], aA);
            hA[j] = fmaf(KD_F, hA[j], aA);
            float aB = fmaf(sB0, mrs[j][0], uBp[j]);
            aB = fmaf(sB1, mrs[j][1], aB);
            aB = fmaf(sB2, mrs[j][2], aB);
            aB = fmaf(sB3, mrs[j][3], aB);
            hB[j] = fmaf(KD_F, hB[j], aB);
        }

        // store raw s_t for the output filter kernel
        if (tid == 0) sA[t] = make_float4(sA0, sA1, sA2, sA3);
        if (tid == 1) sB[t] = make_float4(sB0, sB1, sB2, sB3);

        uAc = uAn; uBc = uBn;
    }
}

// =====================================================================
// Kernel 3: 20-channel leaky-integrator output filter.
//   y_t = 0.9*y_{t-1} + [krec*s_t ; ALPHA*x_t]   (pinv(span)@span = I_20)
// 640 independent (b, channel) scans.
// =====================================================================
__global__ __launch_bounds__(256) void out_filter_kernel(
    const float* __restrict__ sbuf,  // [B, T, 4]
    const float* __restrict__ x,     // [B, T, 16]
    float* __restrict__ out)         // [B, T, 20]
{
    const int idx = blockIdx.x * 256 + threadIdx.x;
    if (idx >= BATCH_ * 20) return;
    const int b = idx / 20;
    const int p = idx % 20;

    const float* src;
    float k;
    if (p < 4) { src = sbuf + (size_t)b * T_ * 4 + p;            k = KREC_F; }
    else       { src = x    + (size_t)b * T_ * INPUT_ + (p - 4); k = ALPHA_F; }
    const int stride = (p < 4) ? 4 : INPUT_;

    float* ob = out + (size_t)b * T_ * 20 + p;
    float y = 0.0f;
    for (int t = 0; t < T_; ++t) {
        y = fmaf(KD_F, y, k * src[(size_t)t * stride]);
        ob[(size_t)t * 20] = y;
    }
}

// =====================================================================
// Fallback (round-2 kernel, inline I@x + inline y) if ws is too small.
// =====================================================================
__global__ __launch_bounds__(256) void rnn_scan_fallback(
    const float* __restrict__ x, const float* __restrict__ m,
    const float* __restrict__ n, const float* __restrict__ imat,
    float* __restrict__ out)
{
    const int b = blockIdx.x, tid = threadIdx.x, wave = tid >> 6, lane = tid & 63;
    float h[4], mrs[4][4], nr[4][4], Irs[4][INPUT_];
#pragma unroll
    for (int j = 0; j < 4; ++j) {
        const int hidx = tid * 4 + j;
        h[j] = 0.0f;
        const float4 mv = *(const float4*)(m + hidx * 4);
        mrs[j][0] = KREC_F*mv.x; mrs[j][1] = KREC_F*mv.y; mrs[j][2] = KREC_F*mv.z; mrs[j][3] = KREC_F*mv.w;
        const float4 nv = *(const float4*)(n + hidx * 4);
        nr[j][0] = nv.x; nr[j][1] = nv.y; nr[j][2] = nv.z; nr[j][3] = nv.w;
#pragma unroll
        for (int q = 0; q < 4; ++q) {
            const float4 iv = *(const float4*)(imat + hidx * INPUT_ + q * 4);
            Irs[j][q*4+0] = ALPHA_F*iv.x; Irs[j][q*4+1] = ALPHA_F*iv.y;
            Irs[j][q*4+2] = ALPHA_F*iv.z; Irs[j][q*4+3] = ALPHA_F*iv.w;
        }
    }
    __shared__ float4 part[2][4];
    const float* xb = x + (size_t)b * T_ * INPUT_;
    float* ob = out + (size_t)b * T_ * 20;
    float y = 0.0f;
    const bool is_xy = (tid >= 4 && tid < 20);
    float xy = is_xy ? xb[tid - 4] : 0.0f;
    for (int t = 0; t < T_; ++t) {
        const float* xt = xb + t * INPUT_;
        float xr[INPUT_];
#pragma unroll
        for (int q = 0; q < 4; ++q) {
            float4 v = ((const float4*)xt)[q];
            xr[q*4+0]=v.x; xr[q*4+1]=v.y; xr[q*4+2]=v.z; xr[q*4+3]=v.w;
        }
        float xy_nxt = 0.0f;
        if (is_xy) { int tn = (t+1<T_)?(t+1):t; xy_nxt = xb[tn*INPUT_+(tid-4)]; }
        float th[4];
#pragma unroll
        for (int j = 0; j < 4; ++j) th[j] = tanh_fast(h[j]);
        float p0=th[0]*nr[0][0], p1=th[0]*nr[0][1], p2=th[0]*nr[0][2], p3=th[0]*nr[0][3];
#pragma unroll
        for (int j = 1; j < 4; ++j) {
            p0=fmaf(th[j],nr[j][0],p0); p1=fmaf(th[j],nr[j][1],p1);
            p2=fmaf(th[j],nr[j][2],p2); p3=fmaf(th[j],nr[j][3],p3);
        }
#define LVL(c) DPP_ADD(p0,c); DPP_ADD(p1,c); DPP_ADD(p2,c); DPP_ADD(p3,c)
        LVL(0x111); LVL(0x112); LVL(0x114); LVL(0x118); LVL(0x142); LVL(0x143);
#undef LVL
        if (lane == 63) part[t & 1][wave] = make_float4(p0, p1, p2, p3);
        __syncthreads();
        const float4 q0=part[t&1][0], q1=part[t&1][1], q2=part[t&1][2], q3=part[t&1][3];
        const float s0=(q0.x+q1.x)+(q2.x+q3.x), s1=(q0.y+q1.y)+(q2.y+q3.y);
        const float s2=(q0.z+q1.z)+(q2.z+q3.z), s3=(q0.w+q1.w)+(q2.w+q3.w);
#pragma unroll
        for (int j = 0; j < 4; ++j) {
            float a = xr[0]*Irs[j][0];
#pragma unroll
            for (int i = 1; i < INPUT_; ++i) a = fmaf(xr[i], Irs[j][i], a);
            a = fmaf(s0,mrs[j][0],a); a = fmaf(s1,mrs[j][1],a);
            a = fmaf(s2,mrs[j][2],a); a = fmaf(s3,mrs[j][3],a);
            h[j] = fmaf(KD_F, h[j], a);
        }
        if (tid < 20) {
            float drive;
            if (tid < 4) { float sv=(tid==0)?s0:(tid==1)?s1:(tid==2)?s2:s3; drive=KREC_F*sv; }
            else drive = ALPHA_F * xy;
            y = fmaf(KD_F, y, drive);
            ob[t * 20 + tid] = y;
        }
        xy = xy_nxt;
    }
}

extern "C" void kernel_launch(void* const* d_in, const int* in_sizes, int n_in,
                              void* d_out, int out_size, void* d_ws, size_t ws_size,
                              hipStream_t stream) {
    const float* x    = (const float*)d_in[0];
    const float* m    = (const float*)d_in[1];
    const float* n    = (const float*)d_in[2];
    const float* imat = (const float*)d_in[3];
    float* out = (float*)d_out;

    if (ws_size >= WS_NEEDED) {
        float* u    = (float*)d_ws;
        float* sbuf = u + U_ELEMS;
        inp_proj_kernel<<<dim3(BATCH_ * T_), dim3(256), 0, stream>>>(x, imat, u);
        rnn_scan2_kernel<<<dim3(BATCH_ / 2), dim3(256), 0, stream>>>(m, n, u, sbuf);
        out_filter_kernel<<<dim3((BATCH_ * 20 + 255) / 256), dim3(256), 0, stream>>>(sbuf, x, out);
    } else {
        rnn_scan_fallback<<<dim3(BATCH_), dim3(256), 0, stream>>>(x, m, n, imat, out);
    }
}

// Round 4
// 870.161 us; speedup vs baseline: 1.3441x; 1.3441x over previous
//
#include <hip/hip_runtime.h>
#include <math.h>

// Problem constants (MixtureLowRankRNN)
#define HIDDEN_ 1024
#define RANK_ 4
#define INPUT_ 16
#define T_ 1024
#define BATCH_ 32

#define ALPHA_F 0.1f
#define KD_F    0.9f                        // 1 - ALPHA
#define KREC_F  (0.1f * (500.0f / 1024.0f)) // ALPHA * BASE_SCALE / HIDDEN

// ---- workspace layout ----
// u    : [B][T][H] floats = ALPHA * x_t @ I^T   (134.2 MB)
// sbuf : [B][T][4] floats = raw s_t partial sums (0.5 MB)
#define U_ELEMS  ((size_t)BATCH_ * T_ * HIDDEN_)
#define S_ELEMS  ((size_t)BATCH_ * T_ * 4)
#define WS_NEEDED ((U_ELEMS + S_ELEMS) * sizeof(float))

__device__ __forceinline__ float fast_exp2(float x) { return __builtin_amdgcn_exp2f(x); }
__device__ __forceinline__ float fast_rcp(float x)  { return __builtin_amdgcn_rcpf(x); }
// tanh(x) = 1 - 2/(exp(2x)+1); ~1e-6 abs err, overflow-safe (-> +-1).
__device__ __forceinline__ float tanh_fast(float x) {
    float e = fast_exp2(x * 2.885390081777926815f); // 2*log2(e)
    return fmaf(-2.0f, fast_rcp(e + 1.0f), 1.0f);
}

// v += dpp_mov(v, ctrl), old=0, bound_ctrl=1 (masked reads contribute 0).
#define DPP_ADD(v, ctrl)                                                        \
    do {                                                                        \
        int _t = __builtin_amdgcn_update_dpp(0, __float_as_int(v), (ctrl), 0xf, \
                                             0xf, true);                        \
        (v) += __int_as_float(_t);                                              \
    } while (0)

__device__ __forceinline__ float readlane63(float v) {
    return __int_as_float(__builtin_amdgcn_readlane(__float_as_int(v), 63));
}

// =====================================================================
// Kernel 1: u[b][t][h] = ALPHA * sum_i x[b][t][i] * I[h][i]
// One block per (b,t); 256 threads x 4 h-elements. Memory-bound on the
// 134 MB u-write.  (unchanged from round 3 — writes coalesced float4)
// =====================================================================
__global__ __launch_bounds__(256) void inp_proj_kernel(
    const float* __restrict__ x, const float* __restrict__ imat,
    float* __restrict__ u)
{
    const int bt  = blockIdx.x;          // 0 .. B*T-1
    const int tid = threadIdx.x;

    __shared__ float xs[INPUT_];
    if (tid < INPUT_) xs[tid] = x[(size_t)bt * INPUT_ + tid];
    __syncthreads();

    float xr[INPUT_];
#pragma unroll
    for (int i = 0; i < INPUT_; ++i) xr[i] = xs[i];

    float o[4];
#pragma unroll
    for (int j = 0; j < 4; ++j) {
        const float* Ih = imat + (size_t)(tid * 4 + j) * INPUT_;
        float a = xr[0] * Ih[0];
#pragma unroll
        for (int i = 1; i < INPUT_; ++i) a = fmaf(xr[i], Ih[i], a);
        o[j] = ALPHA_F * a;
    }
    ((float4*)u)[(size_t)bt * (HIDDEN_ / 4) + tid] =
        make_float4(o[0], o[1], o[2], o[3]);
}

// =====================================================================
// Kernel 2: the scan. ONE WAVE PER BATCH (32 blocks x 64 threads),
// EPT=16 h-elements/lane (h_global = lane*16 + j). No LDS, no barrier:
// rank-4 cross-lane reduce = 6-level DPP chain to lane 63, then
// v_readlane -> SGPR broadcast. u streamed with distance-2 prefetch
// (unroll-2, two 4xfloat4 register buffers; load issued after its
// buffer is consumed, giving ~2 full steps of latency cover).
// Raw s_t written by lane 63 for the output-filter kernel.
// =====================================================================
struct UBuf { float4 v[4]; };

__device__ __forceinline__ void scan_step(
    int t, int tpre, int L,
    float (&h)[16], const float (&mrs)[16][4], const float (&nr)[16][4],
    UBuf& ub_regs, const float4* __restrict__ ub, float4* __restrict__ sB)
{
    // tanh + rank-4 partial dots over this lane's 16 elements
    float t0 = tanh_fast(h[0]);
    float p0 = t0 * nr[0][0], p1 = t0 * nr[0][1];
    float p2 = t0 * nr[0][2], p3 = t0 * nr[0][3];
#pragma unroll
    for (int j = 1; j < 16; ++j) {
        float tj = tanh_fast(h[j]);
        p0 = fmaf(tj, nr[j][0], p0); p1 = fmaf(tj, nr[j][1], p1);
        p2 = fmaf(tj, nr[j][2], p2); p3 = fmaf(tj, nr[j][3], p3);
    }

    // 6-level DPP reduce to lane 63 (verified R2/R3), 4 chains interleaved
#define LVL(c) DPP_ADD(p0, c); DPP_ADD(p1, c); DPP_ADD(p2, c); DPP_ADD(p3, c)
    LVL(0x111); LVL(0x112); LVL(0x114); LVL(0x118); LVL(0x142); LVL(0x143);
#undef LVL

    // broadcast via SGPRs — no LDS, no barrier
    const float s0 = readlane63(p0);
    const float s1 = readlane63(p1);
    const float s2 = readlane63(p2);
    const float s3 = readlane63(p3);

    if (L == 63) sB[t] = make_float4(p0, p1, p2, p3);  // raw s_t

    // h <- kd*h + (krec*m)@s + u_t   (consume prefetched buffer)
#pragma unroll
    for (int k = 0; k < 4; ++k) {
        const float ue[4] = {ub_regs.v[k].x, ub_regs.v[k].y,
                             ub_regs.v[k].z, ub_regs.v[k].w};
#pragma unroll
        for (int c = 0; c < 4; ++c) {
            const int j = k * 4 + c;
            float a = fmaf(s0, mrs[j][0], ue[c]);
            a = fmaf(s1, mrs[j][1], a);
            a = fmaf(s2, mrs[j][2], a);
            a = fmaf(s3, mrs[j][3], a);
            h[j] = fmaf(KD_F, h[j], a);
        }
    }

    // refill this buffer for step t+2 (consumed 2 steps from now)
#pragma unroll
    for (int k = 0; k < 4; ++k)
        ub_regs.v[k] = ub[(size_t)tpre * (HIDDEN_ / 4) + L * 4 + k];
}

__global__ __launch_bounds__(64, 1) void rnn_scan_wave_kernel(
    const float* __restrict__ m,     // [H, 4]
    const float* __restrict__ n,     // [H, 4]
    const float* __restrict__ u,     // [B, T, H] (pre-scaled by ALPHA)
    float* __restrict__ sbuf)        // [B, T, 4]
{
    const int b = blockIdx.x;
    const int L = threadIdx.x;       // 0..63

    float h[16];
    float mrs[16][4];   // krec * m row
    float nr[16][4];

#pragma unroll
    for (int j = 0; j < 16; ++j) {
        const int hidx = L * 16 + j;
        h[j] = 0.0f;
        const float4 mv = *(const float4*)(m + hidx * 4);
        mrs[j][0] = KREC_F * mv.x; mrs[j][1] = KREC_F * mv.y;
        mrs[j][2] = KREC_F * mv.z; mrs[j][3] = KREC_F * mv.w;
        const float4 nv = *(const float4*)(n + hidx * 4);
        nr[j][0] = nv.x; nr[j][1] = nv.y; nr[j][2] = nv.z; nr[j][3] = nv.w;
    }

    const float4* ub = (const float4*)(u + (size_t)b * T_ * HIDDEN_);
    float4* sB = (float4*)sbuf + (size_t)b * T_;

    UBuf uA, uB;
#pragma unroll
    for (int k = 0; k < 4; ++k) {
        uA.v[k] = ub[0 * (HIDDEN_ / 4) + L * 4 + k];   // u_0
        uB.v[k] = ub[1 * (HIDDEN_ / 4) + L * 4 + k];   // u_1
    }

    for (int t = 0; t < T_; t += 2) {
        const int tp0 = (t + 2 < T_) ? t + 2 : T_ - 1;
        const int tp1 = (t + 3 < T_) ? t + 3 : T_ - 1;
        scan_step(t,     tp0, L, h, mrs, nr, uA, ub, sB);
        scan_step(t + 1, tp1, L, h, mrs, nr, uB, ub, sB);
    }
}

// =====================================================================
// Kernel 3: 20-channel leaky integrator, parallelized over T-chunks
// with exponential warm-up (0.9^192 ~ 2e-9 -> exact to fp32 noise).
//   y_t = 0.9*y_{t-1} + [krec*s_t ; ALPHA*x_t]   (pinv(span)@span = I_20)
// 32*20*8 = 5120 independent threads.
// =====================================================================
#define FCHUNK_ 128
#define FWARM_  192
#define NCHUNK_ (T_ / FCHUNK_)   // 8

__global__ __launch_bounds__(256) void out_filter_kernel(
    const float* __restrict__ sbuf,  // [B, T, 4]
    const float* __restrict__ x,     // [B, T, 16]
    float* __restrict__ out)         // [B, T, 20]
{
    const int idx = blockIdx.x * 256 + threadIdx.x;
    if (idx >= BATCH_ * 20 * NCHUNK_) return;
    const int c  = idx % NCHUNK_;
    const int bp = idx / NCHUNK_;
    const int p  = bp % 20;
    const int b  = bp / 20;

    const float* src; int stride; float k;
    if (p < 4) { src = sbuf + (size_t)b * T_ * 4 + p;            stride = 4;      k = KREC_F; }
    else       { src = x    + (size_t)b * T_ * INPUT_ + (p - 4); stride = INPUT_; k = ALPHA_F; }

    const int tstart = c * FCHUNK_;
    int t0 = tstart - FWARM_; if (t0 < 0) t0 = 0;

    float* ob = out + (size_t)b * T_ * 20 + p;
    float y = 0.0f;
    for (int t = t0; t < tstart + FCHUNK_; ++t) {
        y = fmaf(KD_F, y, k * src[(size_t)t * stride]);
        if (t >= tstart) ob[(size_t)t * 20] = y;
    }
}

// =====================================================================
// Fallback (round-2 kernel: inline I@x, inline y, LDS reduce) if ws
// is too small. Known-good at 604 us.
// =====================================================================
__global__ __launch_bounds__(256) void rnn_scan_fallback(
    const float* __restrict__ x, const float* __restrict__ m,
    const float* __restrict__ n, const float* __restrict__ imat,
    float* __restrict__ out)
{
    const int b = blockIdx.x, tid = threadIdx.x, wave = tid >> 6, lane = tid & 63;
    float h[4], mrs[4][4], nr[4][4], Irs[4][INPUT_];
#pragma unroll
    for (int j = 0; j < 4; ++j) {
        const int hidx = tid * 4 + j;
        h[j] = 0.0f;
        const float4 mv = *(const float4*)(m + hidx * 4);
        mrs[j][0] = KREC_F*mv.x; mrs[j][1] = KREC_F*mv.y; mrs[j][2] = KREC_F*mv.z; mrs[j][3] = KREC_F*mv.w;
        const float4 nv = *(const float4*)(n + hidx * 4);
        nr[j][0] = nv.x; nr[j][1] = nv.y; nr[j][2] = nv.z; nr[j][3] = nv.w;
#pragma unroll
        for (int q = 0; q < 4; ++q) {
            const float4 iv = *(const float4*)(imat + hidx * INPUT_ + q * 4);
            Irs[j][q*4+0] = ALPHA_F*iv.x; Irs[j][q*4+1] = ALPHA_F*iv.y;
            Irs[j][q*4+2] = ALPHA_F*iv.z; Irs[j][q*4+3] = ALPHA_F*iv.w;
        }
    }
    __shared__ float4 part[2][4];
    const float* xb = x + (size_t)b * T_ * INPUT_;
    float* ob = out + (size_t)b * T_ * 20;
    float y = 0.0f;
    const bool is_xy = (tid >= 4 && tid < 20);
    float xy = is_xy ? xb[tid - 4] : 0.0f;
    for (int t = 0; t < T_; ++t) {
        const float* xt = xb + t * INPUT_;
        float xr[INPUT_];
#pragma unroll
        for (int q = 0; q < 4; ++q) {
            float4 v = ((const float4*)xt)[q];
            xr[q*4+0]=v.x; xr[q*4+1]=v.y; xr[q*4+2]=v.z; xr[q*4+3]=v.w;
        }
        float xy_nxt = 0.0f;
        if (is_xy) { int tn = (t+1<T_)?(t+1):t; xy_nxt = xb[tn*INPUT_+(tid-4)]; }
        float th[4];
#pragma unroll
        for (int j = 0; j < 4; ++j) th[j] = tanh_fast(h[j]);
        float p0=th[0]*nr[0][0], p1=th[0]*nr[0][1], p2=th[0]*nr[0][2], p3=th[0]*nr[0][3];
#pragma unroll
        for (int j = 1; j < 4; ++j) {
            p0=fmaf(th[j],nr[j][0],p0); p1=fmaf(th[j],nr[j][1],p1);
            p2=fmaf(th[j],nr[j][2],p2); p3=fmaf(th[j],nr[j][3],p3);
        }
#define LVL(c) DPP_ADD(p0,c); DPP_ADD(p1,c); DPP_ADD(p2,c); DPP_ADD(p3,c)
        LVL(0x111); LVL(0x112); LVL(0x114); LVL(0x118); LVL(0x142); LVL(0x143);
#undef LVL
        if (lane == 63) part[t & 1][wave] = make_float4(p0, p1, p2, p3);
        __syncthreads();
        const float4 q0=part[t&1][0], q1=part[t&1][1], q2=part[t&1][2], q3=part[t&1][3];
        const float s0=(q0.x+q1.x)+(q2.x+q3.x), s1=(q0.y+q1.y)+(q2.y+q3.y);
        const float s2=(q0.z+q1.z)+(q2.z+q3.z), s3=(q0.w+q1.w)+(q2.w+q3.w);
#pragma unroll
        for (int j = 0; j < 4; ++j) {
            float a = xr[0]*Irs[j][0];
#pragma unroll
            for (int i = 1; i < INPUT_; ++i) a = fmaf(xr[i], Irs[j][i], a);
            a = fmaf(s0,mrs[j][0],a); a = fmaf(s1,mrs[j][1],a);
            a = fmaf(s2,mrs[j][2],a); a = fmaf(s3,mrs[j][3],a);
            h[j] = fmaf(KD_F, h[j], a);
        }
        if (tid < 20) {
            float drive;
            if (tid < 4) { float sv=(tid==0)?s0:(tid==1)?s1:(tid==2)?s2:s3; drive=KREC_F*sv; }
            else drive = ALPHA_F * xy;
            y = fmaf(KD_F, y, drive);
            ob[t * 20 + tid] = y;
        }
        xy = xy_nxt;
    }
}

extern "C" void kernel_launch(void* const* d_in, const int* in_sizes, int n_in,
                              void* d_out, int out_size, void* d_ws, size_t ws_size,
                              hipStream_t stream) {
    const float* x    = (const float*)d_in[0];
    const float* m    = (const float*)d_in[1];
    const float* n    = (const float*)d_in[2];
    const float* imat = (const float*)d_in[3];
    float* out = (float*)d_out;

    if (ws_size >= WS_NEEDED) {
        float* u    = (float*)d_ws;
        float* sbuf = u + U_ELEMS;
        inp_proj_kernel<<<dim3(BATCH_ * T_), dim3(256), 0, stream>>>(x, imat, u);
        rnn_scan_wave_kernel<<<dim3(BATCH_), dim3(64), 0, stream>>>(m, n, u, sbuf);
        out_filter_kernel<<<dim3((BATCH_ * 20 * NCHUNK_ + 255) / 256), dim3(256), 0, stream>>>(sbuf, x, out);
    } else {
        rnn_scan_fallback<<<dim3(BATCH_), dim3(256), 0, stream>>>(x, m, n, imat, out);
    }
}

// Round 5
// 820.069 us; speedup vs baseline: 1.4262x; 1.0611x over previous
//
#include <hip/hip_runtime.h>
#include <math.h>

// Problem constants (MixtureLowRankRNN)
#define HIDDEN_ 1024
#define RANK_ 4
#define INPUT_ 16
#define T_ 1024
#define BATCH_ 32

#define ALPHA_F 0.1f
#define KD_F    0.9f                        // 1 - ALPHA
#define KREC_F  (0.1f * (500.0f / 1024.0f)) // ALPHA * BASE_SCALE / HIDDEN

// ---- workspace: u[B][T][H] = ALPHA * x_t @ I^T (134.2 MB) ----
#define U_ELEMS   ((size_t)BATCH_ * T_ * HIDDEN_)
#define WS_NEEDED (U_ELEMS * sizeof(float))

typedef float v2f __attribute__((ext_vector_type(2)));

__device__ __forceinline__ float fast_exp2(float x) { return __builtin_amdgcn_exp2f(x); }
__device__ __forceinline__ float fast_rcp(float x)  { return __builtin_amdgcn_rcpf(x); }

// tanh over a packed pair: 3 pk-VALU + 4 trans.  ~1e-6 abs err, overflow-safe.
__device__ __forceinline__ v2f tanh2(v2f x) {
    v2f z = x * 2.885390081777926815f;       // 2*log2(e)  (v_pk_mul_f32)
    v2f e;
    e.x = fast_exp2(z.x);
    e.y = fast_exp2(z.y);
    e = e + 1.0f;                            // v_pk_add_f32
    v2f r;
    r.x = fast_rcp(e.x);
    r.y = fast_rcp(e.y);
    return -2.0f * r + 1.0f;                 // v_pk_fma_f32
}

// v += dpp_mov(v, ctrl), old=0, bound_ctrl=1 (masked reads contribute 0).
#define DPP_ADD(v, ctrl)                                                        \
    do {                                                                        \
        int _t = __builtin_amdgcn_update_dpp(0, __float_as_int(v), (ctrl), 0xf, \
                                             0xf, true);                        \
        (v) += __int_as_float(_t);                                              \
    } while (0)

__device__ __forceinline__ float readlane63(float v) {
    return __int_as_float(__builtin_amdgcn_readlane(__float_as_int(v), 63));
}

// =====================================================================
// Kernel 1: u[b][t][h] = ALPHA * sum_i x[b][t][i] * I[h][i]
// imat rows held in REGISTERS (4 rows/thread), 16 timesteps per block
// -> imat read amortized 16x, coalesced float4 stores. Write-bound.
// =====================================================================
#define PCHUNK_ 16

__global__ __launch_bounds__(256) void inp_proj_kernel(
    const float* __restrict__ x, const float* __restrict__ imat,
    float* __restrict__ u)
{
    const int blk = blockIdx.x;              // 0 .. B*(T/PCHUNK)-1
    const int b   = blk / (T_ / PCHUNK_);
    const int tc  = blk % (T_ / PCHUNK_);
    const int tid = threadIdx.x;

    float Ir[4][INPUT_];                     // rows tid*4 .. tid*4+3, pre-scaled
#pragma unroll
    for (int j = 0; j < 4; ++j) {
#pragma unroll
        for (int q = 0; q < 4; ++q) {
            const float4 iv = *(const float4*)(imat + (size_t)(tid * 4 + j) * INPUT_ + q * 4);
            Ir[j][q*4+0] = ALPHA_F * iv.x; Ir[j][q*4+1] = ALPHA_F * iv.y;
            Ir[j][q*4+2] = ALPHA_F * iv.z; Ir[j][q*4+3] = ALPHA_F * iv.w;
        }
    }

    const float* xb = x + ((size_t)b * T_ + (size_t)tc * PCHUNK_) * INPUT_;
    float4* ub = (float4*)u + ((size_t)b * T_ + (size_t)tc * PCHUNK_) * (HIDDEN_ / 4);

    for (int tt = 0; tt < PCHUNK_; ++tt) {
        float xr[INPUT_];
#pragma unroll
        for (int q = 0; q < 4; ++q) {
            float4 v = ((const float4*)(xb + tt * INPUT_))[q];  // wave-uniform
            xr[q*4+0] = v.x; xr[q*4+1] = v.y; xr[q*4+2] = v.z; xr[q*4+3] = v.w;
        }
        float o[4];
#pragma unroll
        for (int j = 0; j < 4; ++j) {
            float a = xr[0] * Ir[j][0];
#pragma unroll
            for (int i = 1; i < INPUT_; ++i) a = fmaf(xr[i], Ir[j][i], a);
            o[j] = a;
        }
        ub[(size_t)tt * (HIDDEN_ / 4) + tid] = make_float4(o[0], o[1], o[2], o[3]);
    }
}

// =====================================================================
// Kernel 2: the scan + fused output filter. ONE WAVE PER BATCH
// (32 blocks x 64 lanes), EPT=16 (8 packed pairs/lane). No LDS/barrier:
// DPP chain to lane 63 + v_readlane SGPR broadcast. u streamed with
// DISTANCE-4 prefetch (unroll-4, 4 register buffers) to cover ~900 cy
// HBM miss (FETCH showed half of u misses L3). All dense math packed
// (v_pk_fma_f32). Lanes 0..19 integrate y inline and store out.
// =====================================================================
__device__ __forceinline__ void scan_step(
    int t, int tpre, int L,
    v2f (&h)[8], const v2f (&mrs)[8][4], const v2f (&nr)[8][4],
    float4 (&ubuf)[4], const float4* __restrict__ ub,
    bool ylane, bool xlane, float& yacc, float& xy,
    const float* __restrict__ xb, float* __restrict__ outb)
{
    // issue next-step x load for y-lanes early (covered by step body)
    float xy_nxt = 0.0f;
    if (xlane) {
        const int tn = (t + 1 < T_) ? t + 1 : t;
        xy_nxt = xb[(size_t)tn * INPUT_ + (L - 4)];
    }

    // tanh + rank-4 packed partial dots over this lane's 8 pairs
    v2f P0, P1, P2, P3;
    {
        v2f th = tanh2(h[0]);
        P0 = th * nr[0][0]; P1 = th * nr[0][1];
        P2 = th * nr[0][2]; P3 = th * nr[0][3];
    }
#pragma unroll
    for (int k = 1; k < 8; ++k) {
        v2f th = tanh2(h[k]);
        P0 += th * nr[k][0]; P1 += th * nr[k][1];
        P2 += th * nr[k][2]; P3 += th * nr[k][3];
    }
    float p0 = P0.x + P0.y, p1 = P1.x + P1.y;
    float p2 = P2.x + P2.y, p3 = P3.x + P3.y;

    // 6-level DPP reduce to lane 63 (verified R2-R4), 4 chains interleaved
#define LVL(c) DPP_ADD(p0, c); DPP_ADD(p1, c); DPP_ADD(p2, c); DPP_ADD(p3, c)
    LVL(0x111); LVL(0x112); LVL(0x114); LVL(0x118); LVL(0x142); LVL(0x143);
#undef LVL

    const float s0 = readlane63(p0);
    const float s1 = readlane63(p1);
    const float s2 = readlane63(p2);
    const float s3 = readlane63(p3);

    // fused y-filter: y_t = kd*y + [krec*s ; alpha*x_t]   (pinv(span)@span = I_20)
    if (ylane) {
        float drive;
        if (L < 4) {
            float sv = (L == 0) ? s0 : (L == 1) ? s1 : (L == 2) ? s2 : s3;
            drive = KREC_F * sv;
        } else {
            drive = ALPHA_F * xy;
        }
        yacc = fmaf(KD_F, yacc, drive);
        outb[(size_t)t * 20 + L] = yacc;
    }
    xy = xy_nxt;

    // h <- kd*h + (krec*m)@s + u_t   (packed, consume prefetched buffer)
#pragma unroll
    for (int k = 0; k < 8; ++k) {
        const float4& f = ubuf[k >> 1];
        v2f uu;
        uu.x = (k & 1) ? f.z : f.x;
        uu.y = (k & 1) ? f.w : f.y;
        v2f a = s0 * mrs[k][0] + uu;
        a = s1 * mrs[k][1] + a;
        a = s2 * mrs[k][2] + a;
        a = s3 * mrs[k][3] + a;
        h[k] = KD_F * h[k] + a;
    }

    // refill this buffer for step t+4
#pragma unroll
    for (int k = 0; k < 4; ++k)
        ubuf[k] = ub[(size_t)tpre * (HIDDEN_ / 4) + L * 4 + k];
}

__global__ __launch_bounds__(64, 1) void rnn_scan_wave_kernel(
    const float* __restrict__ m,     // [H, 4]
    const float* __restrict__ n,     // [H, 4]
    const float* __restrict__ u,     // [B, T, H] (pre-scaled by ALPHA)
    const float* __restrict__ x,     // [B, T, 16]
    float* __restrict__ out)         // [B, T, 20]
{
    const int b = blockIdx.x;
    const int L = threadIdx.x;       // 0..63

    v2f h[8];
    v2f mrs[8][4];   // krec * m, packed pairs {elem 2k, elem 2k+1}
    v2f nr[8][4];

#pragma unroll
    for (int k = 0; k < 8; ++k) {
        h[k] = 0.0f;
        const int h0 = L * 16 + 2 * k;
        const float4 m0 = *(const float4*)(m + (size_t)h0 * 4);
        const float4 m1 = *(const float4*)(m + (size_t)(h0 + 1) * 4);
        mrs[k][0] = KREC_F * (v2f){m0.x, m1.x};
        mrs[k][1] = KREC_F * (v2f){m0.y, m1.y};
        mrs[k][2] = KREC_F * (v2f){m0.z, m1.z};
        mrs[k][3] = KREC_F * (v2f){m0.w, m1.w};
        const float4 n0 = *(const float4*)(n + (size_t)h0 * 4);
        const float4 n1 = *(const float4*)(n + (size_t)(h0 + 1) * 4);
        nr[k][0] = (v2f){n0.x, n1.x};
        nr[k][1] = (v2f){n0.y, n1.y};
        nr[k][2] = (v2f){n0.z, n1.z};
        nr[k][3] = (v2f){n0.w, n1.w};
    }

    const float4* ub = (const float4*)(u + (size_t)b * T_ * HIDDEN_);
    const float* xb = x + (size_t)b * T_ * INPUT_;
    float* outb = out + (size_t)b * T_ * 20;

    const bool ylane = (L < 20);
    const bool xlane = (L >= 4 && L < 20);
    float yacc = 0.0f;
    float xy = xlane ? xb[L - 4] : 0.0f;    // x[b][0][L-4]

    float4 u0[4], u1[4], u2[4], u3[4];
#pragma unroll
    for (int k = 0; k < 4; ++k) {
        u0[k] = ub[(size_t)0 * (HIDDEN_ / 4) + L * 4 + k];
        u1[k] = ub[(size_t)1 * (HIDDEN_ / 4) + L * 4 + k];
        u2[k] = ub[(size_t)2 * (HIDDEN_ / 4) + L * 4 + k];
        u3[k] = ub[(size_t)3 * (HIDDEN_ / 4) + L * 4 + k];
    }

    for (int t = 0; t < T_; t += 4) {
        const int tp0 = (t + 4 < T_) ? t + 4 : T_ - 1;
        const int tp1 = (t + 5 < T_) ? t + 5 : T_ - 1;
        const int tp2 = (t + 6 < T_) ? t + 6 : T_ - 1;
        const int tp3 = (t + 7 < T_) ? t + 7 : T_ - 1;
        scan_step(t,     tp0, L, h, mrs, nr, u0, ub, ylane, xlane, yacc, xy, xb, outb);
        scan_step(t + 1, tp1, L, h, mrs, nr, u1, ub, ylane, xlane, yacc, xy, xb, outb);
        scan_step(t + 2, tp2, L, h, mrs, nr, u2, ub, ylane, xlane, yacc, xy, xb, outb);
        scan_step(t + 3, tp3, L, h, mrs, nr, u3, ub, ylane, xlane, yacc, xy, xb, outb);
    }
}

// =====================================================================
// Fallback (round-2 kernel: inline I@x, inline y, LDS reduce) if ws
// is too small. Known-good at 604 us.
// =====================================================================
__device__ __forceinline__ float tanh_fast(float x) {
    float e = fast_exp2(x * 2.885390081777926815f);
    return fmaf(-2.0f, fast_rcp(e + 1.0f), 1.0f);
}

__global__ __launch_bounds__(256) void rnn_scan_fallback(
    const float* __restrict__ x, const float* __restrict__ m,
    const float* __restrict__ n, const float* __restrict__ imat,
    float* __restrict__ out)
{
    const int b = blockIdx.x, tid = threadIdx.x, wave = tid >> 6, lane = tid & 63;
    float h[4], mrs[4][4], nr[4][4], Irs[4][INPUT_];
#pragma unroll
    for (int j = 0; j < 4; ++j) {
        const int hidx = tid * 4 + j;
        h[j] = 0.0f;
        const float4 mv = *(const float4*)(m + hidx * 4);
        mrs[j][0] = KREC_F*mv.x; mrs[j][1] = KREC_F*mv.y; mrs[j][2] = KREC_F*mv.z; mrs[j][3] = KREC_F*mv.w;
        const float4 nv = *(const float4*)(n + hidx * 4);
        nr[j][0] = nv.x; nr[j][1] = nv.y; nr[j][2] = nv.z; nr[j][3] = nv.w;
#pragma unroll
        for (int q = 0; q < 4; ++q) {
            const float4 iv = *(const float4*)(imat + hidx * INPUT_ + q * 4);
            Irs[j][q*4+0] = ALPHA_F*iv.x; Irs[j][q*4+1] = ALPHA_F*iv.y;
            Irs[j][q*4+2] = ALPHA_F*iv.z; Irs[j][q*4+3] = ALPHA_F*iv.w;
        }
    }
    __shared__ float4 part[2][4];
    const float* xb = x + (size_t)b * T_ * INPUT_;
    float* ob = out + (size_t)b * T_ * 20;
    float y = 0.0f;
    const bool is_xy = (tid >= 4 && tid < 20);
    float xy = is_xy ? xb[tid - 4] : 0.0f;
    for (int t = 0; t < T_; ++t) {
        const float* xt = xb + t * INPUT_;
        float xr[INPUT_];
#pragma unroll
        for (int q = 0; q < 4; ++q) {
            float4 v = ((const float4*)xt)[q];
            xr[q*4+0]=v.x; xr[q*4+1]=v.y; xr[q*4+2]=v.z; xr[q*4+3]=v.w;
        }
        float xy_nxt = 0.0f;
        if (is_xy) { int tn = (t+1<T_)?(t+1):t; xy_nxt = xb[tn*INPUT_+(tid-4)]; }
        float th[4];
#pragma unroll
        for (int j = 0; j < 4; ++j) th[j] = tanh_fast(h[j]);
        float p0=th[0]*nr[0][0], p1=th[0]*nr[0][1], p2=th[0]*nr[0][2], p3=th[0]*nr[0][3];
#pragma unroll
        for (int j = 1; j < 4; ++j) {
            p0=fmaf(th[j],nr[j][0],p0); p1=fmaf(th[j],nr[j][1],p1);
            p2=fmaf(th[j],nr[j][2],p2); p3=fmaf(th[j],nr[j][3],p3);
        }
#define LVL(c) DPP_ADD(p0,c); DPP_ADD(p1,c); DPP_ADD(p2,c); DPP_ADD(p3,c)
        LVL(0x111); LVL(0x112); LVL(0x114); LVL(0x118); LVL(0x142); LVL(0x143);
#undef LVL
        if (lane == 63) part[t & 1][wave] = make_float4(p0, p1, p2, p3);
        __syncthreads();
        const float4 q0=part[t&1][0], q1=part[t&1][1], q2=part[t&1][2], q3=part[t&1][3];
        const float s0=(q0.x+q1.x)+(q2.x+q3.x), s1=(q0.y+q1.y)+(q2.y+q3.y);
        const float s2=(q0.z+q1.z)+(q2.z+q3.z), s3=(q0.w+q1.w)+(q2.w+q3.w);
#pragma unroll
        for (int j = 0; j < 4; ++j) {
            float a = xr[0]*Irs[j][0];
#pragma unroll
            for (int i = 1; i < INPUT_; ++i) a = fmaf(xr[i], Irs[j][i], a);
            a = fmaf(s0,mrs[j][0],a); a = fmaf(s1,mrs[j][1],a);
            a = fmaf(s2,mrs[j][2],a); a = fmaf(s3,mrs[j][3],a);
            h[j] = fmaf(KD_F, h[j], a);
        }
        if (tid < 20) {
            float drive;
            if (tid < 4) { float sv=(tid==0)?s0:(tid==1)?s1:(tid==2)?s2:s3; drive=KREC_F*sv; }
            else drive = ALPHA_F * xy;
            y = fmaf(KD_F, y, drive);
            ob[t * 20 + tid] = y;
        }
        xy = xy_nxt;
    }
}

extern "C" void kernel_launch(void* const* d_in, const int* in_sizes, int n_in,
                              void* d_out, int out_size, void* d_ws, size_t ws_size,
                              hipStream_t stream) {
    const float* x    = (const float*)d_in[0];
    const float* m    = (const float*)d_in[1];
    const float* n    = (const float*)d_in[2];
    const float* imat = (const float*)d_in[3];
    float* out = (float*)d_out;

    if (ws_size >= WS_NEEDED) {
        float* u = (float*)d_ws;
        inp_proj_kernel<<<dim3(BATCH_ * (T_ / PCHUNK_)), dim3(256), 0, stream>>>(x, imat, u);
        rnn_scan_wave_kernel<<<dim3(BATCH_), dim3(64), 0, stream>>>(m, n, u, x, out);
    } else {
        rnn_scan_fallback<<<dim3(BATCH_), dim3(256), 0, stream>>>(x, m, n, imat, out);
    }
}

// Round 6
// 675.705 us; speedup vs baseline: 1.7308x; 1.2136x over previous
//
#include <hip/hip_runtime.h>
#include <math.h>

// Problem constants (MixtureLowRankRNN)
#define HIDDEN_ 1024
#define RANK_ 4
#define INPUT_ 16
#define T_ 1024
#define BATCH_ 32

#define ALPHA_F 0.1f
#define KD_F    0.9f                        // 1 - ALPHA
#define KREC_F  (0.1f * (500.0f / 1024.0f)) // ALPHA * BASE_SCALE / HIDDEN

// ---- workspace layout ----
// u    : [B][T][H] floats = ALPHA * x_t @ I^T   (134.2 MB)
// sbuf : [B][T][4] floats = raw s_t             (0.5 MB)
#define U_ELEMS   ((size_t)BATCH_ * T_ * HIDDEN_)
#define S_ELEMS   ((size_t)BATCH_ * T_ * 4)
#define WS_NEEDED ((U_ELEMS + S_ELEMS) * sizeof(float))

typedef float v2f __attribute__((ext_vector_type(2)));

__device__ __forceinline__ float fast_exp2(float x) { return __builtin_amdgcn_exp2f(x); }
__device__ __forceinline__ float fast_rcp(float x)  { return __builtin_amdgcn_rcpf(x); }

// packed tanh: 3 pk-VALU + 4 trans ops. ~1e-6 abs err, overflow-safe (-> +-1).
__device__ __forceinline__ v2f tanh2(v2f x) {
    v2f z = x * 2.885390081777926815f;       // 2*log2(e)
    v2f e;
    e.x = fast_exp2(z.x);
    e.y = fast_exp2(z.y);
    e = e + 1.0f;
    v2f r;
    r.x = fast_rcp(e.x);
    r.y = fast_rcp(e.y);
    return -2.0f * r + 1.0f;                 // v_pk_fma_f32
}

// v += dpp_mov(v, ctrl), old=0, bound_ctrl=1 (masked reads contribute 0).
#define DPP_ADD(v, ctrl)                                                        \
    do {                                                                        \
        int _t = __builtin_amdgcn_update_dpp(0, __float_as_int(v), (ctrl), 0xf, \
                                             0xf, true);                        \
        (v) += __int_as_float(_t);                                              \
    } while (0)

__device__ __forceinline__ float readlane63(float v) {
    return __int_as_float(__builtin_amdgcn_readlane(__float_as_int(v), 63));
}

// =====================================================================
// Kernel 1: u[b][t][h] = ALPHA * sum_i x[b][t][i] * I[h][i]
// imat rows in registers (4 rows/thread), 16 timesteps/block.
// Measured round 5: fast (total non-scan overhead 92 us).
// =====================================================================
#define PCHUNK_ 16

__global__ __launch_bounds__(256) void inp_proj_kernel(
    const float* __restrict__ x, const float* __restrict__ imat,
    float* __restrict__ u)
{
    const int blk = blockIdx.x;              // 0 .. B*(T/PCHUNK)-1
    const int b   = blk / (T_ / PCHUNK_);
    const int tc  = blk % (T_ / PCHUNK_);
    const int tid = threadIdx.x;

    float Ir[4][INPUT_];                     // rows tid*4..tid*4+3, pre-scaled
#pragma unroll
    for (int j = 0; j < 4; ++j) {
#pragma unroll
        for (int q = 0; q < 4; ++q) {
            const float4 iv = *(const float4*)(imat + (size_t)(tid * 4 + j) * INPUT_ + q * 4);
            Ir[j][q*4+0] = ALPHA_F * iv.x; Ir[j][q*4+1] = ALPHA_F * iv.y;
            Ir[j][q*4+2] = ALPHA_F * iv.z; Ir[j][q*4+3] = ALPHA_F * iv.w;
        }
    }

    const float* xb = x + ((size_t)b * T_ + (size_t)tc * PCHUNK_) * INPUT_;
    float4* ub = (float4*)u + ((size_t)b * T_ + (size_t)tc * PCHUNK_) * (HIDDEN_ / 4);

    for (int tt = 0; tt < PCHUNK_; ++tt) {
        float xr[INPUT_];
#pragma unroll
        for (int q = 0; q < 4; ++q) {
            float4 v = ((const float4*)(xb + tt * INPUT_))[q];  // wave-uniform
            xr[q*4+0] = v.x; xr[q*4+1] = v.y; xr[q*4+2] = v.z; xr[q*4+3] = v.w;
        }
        float o[4];
#pragma unroll
        for (int j = 0; j < 4; ++j) {
            float a = xr[0] * Ir[j][0];
#pragma unroll
            for (int i = 1; i < INPUT_; ++i) a = fmaf(xr[i], Ir[j][i], a);
            o[j] = a;
        }
        ub[(size_t)tt * (HIDDEN_ / 4) + tid] = make_float4(o[0], o[1], o[2], o[3]);
    }
}

// =====================================================================
// Kernel 2: the scan. R4 champion skeleton (one wave per batch,
// 32 blocks x 64 lanes, EPT=16; distance-2 prefetch, unroll-2; only
// vmem in loop = 4 u-loads + lane-63 sbuf store) with ONE change:
// packed f32 math (v_pk_fma) for tanh/partials/h-update.
// DPP chain to lane 63 + v_readlane broadcast; no LDS, no barrier.
// =====================================================================
struct UBuf { float4 v[4]; };

__device__ __forceinline__ void scan_step(
    int t, int tpre, int L,
    v2f (&h)[8], const v2f (&mrs)[8][4], const v2f (&nr)[8][4],
    UBuf& ubuf, const float4* __restrict__ ub, float4* __restrict__ sB)
{
    // tanh + rank-4 packed partial dots over this lane's 8 pairs
    v2f P0, P1, P2, P3;
    {
        v2f th = tanh2(h[0]);
        P0 = th * nr[0][0]; P1 = th * nr[0][1];
        P2 = th * nr[0][2]; P3 = th * nr[0][3];
    }
#pragma unroll
    for (int k = 1; k < 8; ++k) {
        v2f th = tanh2(h[k]);
        P0 += th * nr[k][0]; P1 += th * nr[k][1];
        P2 += th * nr[k][2]; P3 += th * nr[k][3];
    }
    float p0 = P0.x + P0.y, p1 = P1.x + P1.y;
    float p2 = P2.x + P2.y, p3 = P3.x + P3.y;

    // 6-level DPP reduce to lane 63 (verified R2-R5), 4 chains interleaved
#define LVL(c) DPP_ADD(p0, c); DPP_ADD(p1, c); DPP_ADD(p2, c); DPP_ADD(p3, c)
    LVL(0x111); LVL(0x112); LVL(0x114); LVL(0x118); LVL(0x142); LVL(0x143);
#undef LVL

    const float s0 = readlane63(p0);
    const float s1 = readlane63(p1);
    const float s2 = readlane63(p2);
    const float s3 = readlane63(p3);

    if (L == 63) sB[t] = make_float4(p0, p1, p2, p3);   // raw s_t

    // h <- kd*h + (krec*m)@s + u_t   (packed; consume prefetched buffer)
#pragma unroll
    for (int k = 0; k < 8; ++k) {
        const float4& f = ubuf.v[k >> 1];
        v2f uu;
        uu.x = (k & 1) ? f.z : f.x;
        uu.y = (k & 1) ? f.w : f.y;
        v2f a = s0 * mrs[k][0] + uu;
        a = s1 * mrs[k][1] + a;
        a = s2 * mrs[k][2] + a;
        a = s3 * mrs[k][3] + a;
        h[k] = KD_F * h[k] + a;
    }

    // refill this buffer for step t+2
#pragma unroll
    for (int k = 0; k < 4; ++k)
        ubuf.v[k] = ub[(size_t)tpre * (HIDDEN_ / 4) + L * 4 + k];
}

__global__ __launch_bounds__(64, 1) void rnn_scan_wave_kernel(
    const float* __restrict__ m,     // [H, 4]
    const float* __restrict__ n,     // [H, 4]
    const float* __restrict__ u,     // [B, T, H] (pre-scaled by ALPHA)
    float* __restrict__ sbuf)        // [B, T, 4]
{
    const int b = blockIdx.x;
    const int L = threadIdx.x;       // 0..63

    v2f h[8];
    v2f mrs[8][4];   // krec * m, packed pairs {elem 2k, elem 2k+1}
    v2f nr[8][4];

#pragma unroll
    for (int k = 0; k < 8; ++k) {
        h[k] = 0.0f;
        const int h0 = L * 16 + 2 * k;
        const float4 m0 = *(const float4*)(m + (size_t)h0 * 4);
        const float4 m1 = *(const float4*)(m + (size_t)(h0 + 1) * 4);
        mrs[k][0] = KREC_F * (v2f){m0.x, m1.x};
        mrs[k][1] = KREC_F * (v2f){m0.y, m1.y};
        mrs[k][2] = KREC_F * (v2f){m0.z, m1.z};
        mrs[k][3] = KREC_F * (v2f){m0.w, m1.w};
        const float4 n0 = *(const float4*)(n + (size_t)h0 * 4);
        const float4 n1 = *(const float4*)(n + (size_t)(h0 + 1) * 4);
        nr[k][0] = (v2f){n0.x, n1.x};
        nr[k][1] = (v2f){n0.y, n1.y};
        nr[k][2] = (v2f){n0.z, n1.z};
        nr[k][3] = (v2f){n0.w, n1.w};
    }

    const float4* ub = (const float4*)(u + (size_t)b * T_ * HIDDEN_);
    float4* sB = (float4*)sbuf + (size_t)b * T_;

    UBuf uA, uB;
#pragma unroll
    for (int k = 0; k < 4; ++k) {
        uA.v[k] = ub[(size_t)0 * (HIDDEN_ / 4) + L * 4 + k];   // u_0
        uB.v[k] = ub[(size_t)1 * (HIDDEN_ / 4) + L * 4 + k];   // u_1
    }

    for (int t = 0; t < T_; t += 2) {
        const int tp0 = (t + 2 < T_) ? t + 2 : T_ - 1;
        const int tp1 = (t + 3 < T_) ? t + 3 : T_ - 1;
        scan_step(t,     tp0, L, h, mrs, nr, uA, ub, sB);
        scan_step(t + 1, tp1, L, h, mrs, nr, uB, ub, sB);
    }
}

// =====================================================================
// Kernel 3: 20-channel leaky integrator, chunked with exponential
// warm-up (0.9^192 ~ 2e-9 -> exact to fp32 noise). 5120 ind. threads.
//   y_t = 0.9*y_{t-1} + [krec*s_t ; ALPHA*x_t]   (pinv(span)@span = I_20)
// =====================================================================
#define FCHUNK_ 128
#define FWARM_  192
#define NCHUNK_ (T_ / FCHUNK_)   // 8

__global__ __launch_bounds__(256) void out_filter_kernel(
    const float* __restrict__ sbuf,  // [B, T, 4]
    const float* __restrict__ x,     // [B, T, 16]
    float* __restrict__ out)         // [B, T, 20]
{
    const int idx = blockIdx.x * 256 + threadIdx.x;
    if (idx >= BATCH_ * 20 * NCHUNK_) return;
    const int c  = idx % NCHUNK_;
    const int bp = idx / NCHUNK_;
    const int p  = bp % 20;
    const int b  = bp / 20;

    const float* src; int stride; float k;
    if (p < 4) { src = sbuf + (size_t)b * T_ * 4 + p;            stride = 4;      k = KREC_F; }
    else       { src = x    + (size_t)b * T_ * INPUT_ + (p - 4); stride = INPUT_; k = ALPHA_F; }

    const int tstart = c * FCHUNK_;
    int t0 = tstart - FWARM_; if (t0 < 0) t0 = 0;

    float* ob = out + (size_t)b * T_ * 20 + p;
    float y = 0.0f;
    for (int t = t0; t < tstart + FCHUNK_; ++t) {
        y = fmaf(KD_F, y, k * src[(size_t)t * stride]);
        if (t >= tstart) ob[(size_t)t * 20] = y;
    }
}

// =====================================================================
// Fallback (round-2 kernel) if ws is too small. Known-good at 604 us.
// =====================================================================
__device__ __forceinline__ float tanh_fast(float x) {
    float e = fast_exp2(x * 2.885390081777926815f);
    return fmaf(-2.0f, fast_rcp(e + 1.0f), 1.0f);
}

__global__ __launch_bounds__(256) void rnn_scan_fallback(
    const float* __restrict__ x, const float* __restrict__ m,
    const float* __restrict__ n, const float* __restrict__ imat,
    float* __restrict__ out)
{
    const int b = blockIdx.x, tid = threadIdx.x, wave = tid >> 6, lane = tid & 63;
    float h[4], mrs[4][4], nr[4][4], Irs[4][INPUT_];
#pragma unroll
    for (int j = 0; j < 4; ++j) {
        const int hidx = tid * 4 + j;
        h[j] = 0.0f;
        const float4 mv = *(const float4*)(m + hidx * 4);
        mrs[j][0] = KREC_F*mv.x; mrs[j][1] = KREC_F*mv.y; mrs[j][2] = KREC_F*mv.z; mrs[j][3] = KREC_F*mv.w;
        const float4 nv = *(const float4*)(n + hidx * 4);
        nr[j][0] = nv.x; nr[j][1] = nv.y; nr[j][2] = nv.z; nr[j][3] = nv.w;
#pragma unroll
        for (int q = 0; q < 4; ++q) {
            const float4 iv = *(const float4*)(imat + hidx * INPUT_ + q * 4);
            Irs[j][q*4+0] = ALPHA_F*iv.x; Irs[j][q*4+1] = ALPHA_F*iv.y;
            Irs[j][q*4+2] = ALPHA_F*iv.z; Irs[j][q*4+3] = ALPHA_F*iv.w;
        }
    }
    __shared__ float4 part[2][4];
    const float* xb = x + (size_t)b * T_ * INPUT_;
    float* ob = out + (size_t)b * T_ * 20;
    float y = 0.0f;
    const bool is_xy = (tid >= 4 && tid < 20);
    float xy = is_xy ? xb[tid - 4] : 0.0f;
    for (int t = 0; t < T_; ++t) {
        const float* xt = xb + t * INPUT_;
        float xr[INPUT_];
#pragma unroll
        for (int q = 0; q < 4; ++q) {
            float4 v = ((const float4*)xt)[q];
            xr[q*4+0]=v.x; xr[q*4+1]=v.y; xr[q*4+2]=v.z; xr[q*4+3]=v.w;
        }
        float xy_nxt = 0.0f;
        if (is_xy) { int tn = (t+1<T_)?(t+1):t; xy_nxt = xb[tn*INPUT_+(tid-4)]; }
        float th[4];
#pragma unroll
        for (int j = 0; j < 4; ++j) th[j] = tanh_fast(h[j]);
        float p0=th[0]*nr[0][0], p1=th[0]*nr[0][1], p2=th[0]*nr[0][2], p3=th[0]*nr[0][3];
#pragma unroll
        for (int j = 1; j < 4; ++j) {
            p0=fmaf(th[j],nr[j][0],p0); p1=fmaf(th[j],nr[j][1],p1);
            p2=fmaf(th[j],nr[j][2],p2); p3=fmaf(th[j],nr[j][3],p3);
        }
#define LVL(c) DPP_ADD(p0,c); DPP_ADD(p1,c); DPP_ADD(p2,c); DPP_ADD(p3,c)
        LVL(0x111); LVL(0x112); LVL(0x114); LVL(0x118); LVL(0x142); LVL(0x143);
#undef LVL
        if (lane == 63) part[t & 1][wave] = make_float4(p0, p1, p2, p3);
        __syncthreads();
        const float4 q0=part[t&1][0], q1=part[t&1][1], q2=part[t&1][2], q3=part[t&1][3];
        const float s0=(q0.x+q1.x)+(q2.x+q3.x), s1=(q0.y+q1.y)+(q2.y+q3.y);
        const float s2=(q0.z+q1.z)+(q2.z+q3.z), s3=(q0.w+q1.w)+(q2.w+q3.w);
#pragma unroll
        for (int j = 0; j < 4; ++j) {
            float a = xr[0]*Irs[j][0];
#pragma unroll
            for (int i = 1; i < INPUT_; ++i) a = fmaf(xr[i], Irs[j][i], a);
            a = fmaf(s0,mrs[j][0],a); a = fmaf(s1,mrs[j][1],a);
            a = fmaf(s2,mrs[j][2],a); a = fmaf(s3,mrs[j][3],a);
            h[j] = fmaf(KD_F, h[j], a);
        }
        if (tid < 20) {
            float drive;
            if (tid < 4) { float sv=(tid==0)?s0:(tid==1)?s1:(tid==2)?s2:s3; drive=KREC_F*sv; }
            else drive = ALPHA_F * xy;
            y = fmaf(KD_F, y, drive);
            ob[t * 20 + tid] = y;
        }
        xy = xy_nxt;
    }
}

extern "C" void kernel_launch(void* const* d_in, const int* in_sizes, int n_in,
                              void* d_out, int out_size, void* d_ws, size_t ws_size,
                              hipStream_t stream) {
    const float* x    = (const float*)d_in[0];
    const float* m    = (const float*)d_in[1];
    const float* n    = (const float*)d_in[2];
    const float* imat = (const float*)d_in[3];
    float* out = (float*)d_out;

    if (ws_size >= WS_NEEDED) {
        float* u    = (float*)d_ws;
        float* sbuf = u + U_ELEMS;
        inp_proj_kernel<<<dim3(BATCH_ * (T_ / PCHUNK_)), dim3(256), 0, stream>>>(x, imat, u);
        rnn_scan_wave_kernel<<<dim3(BATCH_), dim3(64), 0, stream>>>(m, n, u, sbuf);
        out_filter_kernel<<<dim3((BATCH_ * 20 * NCHUNK_ + 255) / 256), dim3(256), 0, stream>>>(sbuf, x, out);
    } else {
        rnn_scan_fallback<<<dim3(BATCH_), dim3(256), 0, stream>>>(x, m, n, imat, out);
    }
}